// Round 7
// baseline (25.990 us; speedup 1.0000x reference)
//
#include <hip/hip_runtime.h>

typedef _Float16 hh2 __attribute__((ext_vector_type(2)));

#define DH 40
#define DW 40
#define DT 40
#define NC 96
#define NH 6
#define HD 16
#define NTOK 27
#define NVOX (DH * DW * DT)

// Tile: one head x (8 x 4 x 8) voxels; block = 256 threads, 3 jobs/block.
#define TX 8
#define TY 4
#define TZ 8
#define HX 10
#define HY 6
#define HZ 10
#define NHALO (HX * HY * HZ)       // 600
#define ROW_I4 3                   // 48B LDS row: 32B f16 + 16B pad

#define TXN (DH / TX)              // 5
#define TYN (DW / TY)              // 10
#define TZN (DT / TZ)              // 5
#define NTILE (TXN * TYN * TZN)    // 250
#define NJOB (NTILE * NH)          // 1500
#define JPB 3
#define NBLK (NJOB / JPB)          // 500
#define GRID 512                   // 64 per XCD

__device__ __forceinline__ float dot2acc(hh2 a, hh2 b, float c) {
    return __builtin_amdgcn_fdot2(a, b, c, false);
}
__device__ __forceinline__ hh2 pkrtz(float a, float b) {
    return __builtin_bit_cast(hh2, __builtin_amdgcn_cvt_pkrtz(a, b));
}

union I4H {
    int4 v[2];
    hh2 h[8];
};

__global__ __launch_bounds__(256, 2) void natt_disp_kernel(
    const float* __restrict__ q,
    const float* __restrict__ k,
    const float* __restrict__ rpb,
    float* __restrict__ out)
{
    __shared__ int4 s_k[NHALO * ROW_I4];   // 28.8 KB

    // XCD swizzle (512 % 8 == 0 -> bijective): 64 consecutive blocks per XCD.
    const int sb = ((blockIdx.x & 7) << 6) | (blockIdx.x >> 3);
    if (sb >= NBLK) return;
    const int jbase = sb * JPB;

    const int tid = threadIdx.x;
    const int lz = tid & (TZ - 1);
    const int ly = (tid >> 3) & (TY - 1);
    const int lx = tid >> 5;

    // Static halo-slot decode (job-independent): n = tid, tid+256, tid+512.
    int voff_[3];
    int hx_[3], hy_[3], hz_[3];
    bool has_[3];
    #pragma unroll
    for (int s = 0; s < 3; ++s) {
        const int n = tid + (s << 8);
        has_[s] = (n < NHALO);
        const int hx = n / (HY * HZ);
        const int r  = n - hx * (HY * HZ);
        const int hy = r / HZ;
        const int hz = r - hy * HZ;
        hx_[s] = hx; hy_[s] = hy; hz_[s] = hz;
        voff_[s] = ((hx * DW + hy) * DT + hz) * NC;
    }

    auto params = [&](int t, int& hh, int& x0, int& y0, int& z0) {
        const int job = jbase + t;
        hh = job % NH;
        const int tile = job / NH;
        const int tz = tile % TZN;
        const int ty = (tile / TZN) % TYN;
        const int tx = tile / (TZN * TYN);
        x0 = tx * TX; y0 = ty * TY; z0 = tz * TZ;
    };

    // Issue all global loads for a job into registers (no waits here).
    auto issue = [&](int hh, int x0, int y0, int z0,
                     float4 (&F)[3][4], bool (&ok)[3], float4 (&Q)[4], int& vox) {
        const int base0 = (((x0 - 1) * DW + (y0 - 1)) * DT + (z0 - 1)) * NC + hh * HD;
        #pragma unroll
        for (int s = 0; s < 3; ++s) {
            const bool valid = has_[s]
                & ((unsigned)(x0 - 1 + hx_[s]) < DH)
                & ((unsigned)(y0 - 1 + hy_[s]) < DW)
                & ((unsigned)(z0 - 1 + hz_[s]) < DT);
            ok[s] = valid;
            const int off = valid ? base0 + voff_[s] : 0;
            const float* src = k + off;
            F[s][0] = *(const float4*)(src);
            F[s][1] = *(const float4*)(src + 4);
            F[s][2] = *(const float4*)(src + 8);
            F[s][3] = *(const float4*)(src + 12);
        }
        vox = ((x0 + lx) * DW + (y0 + ly)) * DT + (z0 + lz);
        const float* qs = q + (size_t)vox * NC + hh * HD;
        Q[0] = *(const float4*)(qs);
        Q[1] = *(const float4*)(qs + 4);
        Q[2] = *(const float4*)(qs + 8);
        Q[3] = *(const float4*)(qs + 12);
    };

    // Convert staged registers and write to LDS; convert q to f16.
    auto commit = [&](float4 (&F)[3][4], bool (&ok)[3], float4 (&Q)[4], hh2 (&qh)[8]) {
        #pragma unroll
        for (int s = 0; s < 3; ++s) {
            if (has_[s]) {
                I4H u;
                u.h[0] = pkrtz(F[s][0].x, F[s][0].y);
                u.h[1] = pkrtz(F[s][0].z, F[s][0].w);
                u.h[2] = pkrtz(F[s][1].x, F[s][1].y);
                u.h[3] = pkrtz(F[s][1].z, F[s][1].w);
                u.h[4] = pkrtz(F[s][2].x, F[s][2].y);
                u.h[5] = pkrtz(F[s][2].z, F[s][2].w);
                u.h[6] = pkrtz(F[s][3].x, F[s][3].y);
                u.h[7] = pkrtz(F[s][3].z, F[s][3].w);
                const int4 z4 = make_int4(0, 0, 0, 0);
                if (!ok[s]) { u.v[0] = z4; u.v[1] = z4; }
                const int n = tid + (s << 8);
                s_k[n * ROW_I4 + 0] = u.v[0];
                s_k[n * ROW_I4 + 1] = u.v[1];
            }
        }
        qh[0] = pkrtz(Q[0].x, Q[0].y);
        qh[1] = pkrtz(Q[0].z, Q[0].w);
        qh[2] = pkrtz(Q[1].x, Q[1].y);
        qh[3] = pkrtz(Q[1].z, Q[1].w);
        qh[4] = pkrtz(Q[2].x, Q[2].y);
        qh[5] = pkrtz(Q[2].z, Q[2].w);
        qh[6] = pkrtz(Q[3].x, Q[3].y);
        qh[7] = pkrtz(Q[3].z, Q[3].w);
    };

    auto compute = [&](int hh, hh2 (&qh)[8], int vox) {
        const float* rb = rpb + hh * NTOK;   // block-uniform -> s_load
        float rk[NTOK];
        #pragma unroll
        for (int kk = 0; kk < NTOK; ++kk) rk[kk] = rb[kk];

        float l[NTOK];
        #pragma unroll
        for (int i = 0; i < 3; ++i) {
            #pragma unroll
            for (int j = 0; j < 3; ++j) {
                const int base = ((lx + i) * HY + (ly + j)) * HZ + lz;
                #pragma unroll
                for (int ll = 0; ll < 3; ++ll) {
                    const int n = base + ll;
                    I4H u;
                    u.v[0] = s_k[n * ROW_I4 + 0];
                    u.v[1] = s_k[n * ROW_I4 + 1];
                    float d = 0.0f;
                    d = dot2acc(qh[0], u.h[0], d);
                    d = dot2acc(qh[1], u.h[1], d);
                    d = dot2acc(qh[2], u.h[2], d);
                    d = dot2acc(qh[3], u.h[3], d);
                    d = dot2acc(qh[4], u.h[4], d);
                    d = dot2acc(qh[5], u.h[5], d);
                    d = dot2acc(qh[6], u.h[6], d);
                    d = dot2acc(qh[7], u.h[7], d);
                    const int kk = (i * 3 + j) * 3 + ll;
                    l[kk] = fmaf(d, 0.25f, rk[kk]);   // scale = 16^-0.5
                }
            }
        }

        float g0 = fmaxf(fmaxf(l[0],  l[1]),  l[2]);
        float g1 = fmaxf(fmaxf(l[3],  l[4]),  l[5]);
        float g2 = fmaxf(fmaxf(l[6],  l[7]),  l[8]);
        float g3 = fmaxf(fmaxf(l[9],  l[10]), l[11]);
        float g4 = fmaxf(fmaxf(l[12], l[13]), l[14]);
        float g5 = fmaxf(fmaxf(l[15], l[16]), l[17]);
        float g6 = fmaxf(fmaxf(l[18], l[19]), l[20]);
        float g7 = fmaxf(fmaxf(l[21], l[22]), l[23]);
        float g8 = fmaxf(fmaxf(l[24], l[25]), l[26]);
        float t0 = fmaxf(fmaxf(g0, g1), g2);
        float t1 = fmaxf(fmaxf(g3, g4), g5);
        float t2 = fmaxf(fmaxf(g6, g7), g8);
        const float m = fmaxf(fmaxf(t0, t1), t2);

        const float LOG2E = 1.44269504f;
        const float nm2 = -m * LOG2E;
        float e[NTOK];
        #pragma unroll
        for (int kk = 0; kk < NTOK; ++kk)
            e[kk] = exp2f(fmaf(l[kk], LOG2E, nm2));

        float s[9], zp[9];
        #pragma unroll
        for (int g = 0; g < 9; ++g) {
            s[g]  = (e[g * 3] + e[g * 3 + 1]) + e[g * 3 + 2];
            zp[g] = e[g * 3 + 2] - e[g * 3];
        }
        const float sum = ((s[0] + s[1]) + (s[2] + s[3]))
                        + ((s[4] + s[5]) + (s[6] + s[7])) + s[8];
        const float szs = ((zp[0] + zp[1]) + (zp[2] + zp[3]))
                        + ((zp[4] + zp[5]) + (zp[6] + zp[7])) + zp[8];
        const float sxs = ((s[6] + s[7]) + s[8]) - ((s[0] + s[1]) + s[2]);
        const float sys = ((s[2] + s[5]) + s[8]) - ((s[0] + s[3]) + s[6]);

        const float inv = __builtin_amdgcn_rcpf(sum);

        out[((size_t)(hh * 3 + 0)) * NVOX + vox] = sxs * inv;
        out[((size_t)(hh * 3 + 1)) * NVOX + vox] = sys * inv;
        out[((size_t)(hh * 3 + 2)) * NVOX + vox] = szs * inv;
    };

    // ---- software pipeline over 3 jobs ----
    int ha, xa, ya, za; params(0, ha, xa, ya, za);
    float4 Fa[3][4], Qa[4]; bool oka[3]; int voxa;
    issue(ha, xa, ya, za, Fa, oka, Qa, voxa);
    hh2 qha[8];
    commit(Fa, oka, Qa, qha);
    __syncthreads();

    int hb, xb, yb, zb; params(1, hb, xb, yb, zb);
    float4 Fb[3][4], Qb[4]; bool okb[3]; int voxb;
    issue(hb, xb, yb, zb, Fb, okb, Qb, voxb);   // loads in flight during compute
    compute(ha, qha, voxa);
    __syncthreads();
    hh2 qhb[8];
    commit(Fb, okb, Qb, qhb);
    __syncthreads();

    int hc, xc, yc, zc; params(2, hc, xc, yc, zc);
    float4 Fc[3][4], Qc[4]; bool okc[3]; int voxc;
    issue(hc, xc, yc, zc, Fc, okc, Qc, voxc);
    compute(hb, qhb, voxb);
    __syncthreads();
    hh2 qhc[8];
    commit(Fc, okc, Qc, qhc);
    __syncthreads();

    compute(hc, qhc, voxc);
}

extern "C" void kernel_launch(void* const* d_in, const int* in_sizes, int n_in,
                              void* d_out, int out_size, void* d_ws, size_t ws_size,
                              hipStream_t stream) {
    const float* q   = (const float*)d_in[0];
    const float* k   = (const float*)d_in[1];
    const float* rpb = (const float*)d_in[2];
    float* out = (float*)d_out;

    natt_disp_kernel<<<GRID, 256, 0, stream>>>(q, k, rpb, out);
}

// Round 8
// 21.483 us; speedup vs baseline: 1.2098x; 1.2098x over previous
//
#include <hip/hip_runtime.h>

typedef _Float16 hh2 __attribute__((ext_vector_type(2)));

#define DH 40
#define DW 40
#define DT 40
#define NC 96
#define NH 6
#define HD 16
#define NTOK 27
#define NVOX (DH * DW * DT)

// Tile: one head x (8 x 4 x 8) voxels, 256 threads, thread = 1 voxel.
#define TX 8
#define TY 4
#define TZ 8
#define HX 10
#define HY 6
#define HZ 10
#define NHALO (HX * HY * HZ)       // 600

#define TXN (DH / TX)              // 5
#define TYN (DW / TY)              // 10
#define TZN (DT / TZ)              // 5
#define NTILE (TXN * TYN * TZN)    // 250
#define NJOB (NTILE * NH)          // 1500
#define NXCD 8
#define GRID 1504
#define PER_XCD (GRID / NXCD)      // 188

__device__ __forceinline__ float dot2acc(hh2 a, hh2 b, float c) {
    return __builtin_amdgcn_fdot2(a, b, c, false);
}
__device__ __forceinline__ hh2 pkrtz(float a, float b) {
    return __builtin_bit_cast(hh2, __builtin_amdgcn_cvt_pkrtz(a, b));
}

union I4H {
    int4 v[2];
    hh2 h[8];
};

__global__ __launch_bounds__(256) void natt_disp_kernel(
    const float* __restrict__ q,
    const float* __restrict__ k,
    const float* __restrict__ rpb,
    float* __restrict__ out)
{
    // Dense 32B rows, XOR-swizzled at 16B-chunk granularity by row parity:
    // voxel n (= r*10+zc, r = hx*6+hy) stores chunk h at index (2n+h)^(r&1).
    // Per ds_read_b128 a wave's 64 lanes then land 2 per bank (free level).
    __shared__ int4 s_k[NHALO * 2];    // 19.2 KB

    // XCD swizzle: consecutive blockIdx round-robin across 8 XCDs; chunked
    // job space keeps the 6 head-blocks of a tile on one XCD's L2.
    const int job = (blockIdx.x & (NXCD - 1)) * PER_XCD + (blockIdx.x >> 3);
    if (job >= NJOB) return;   // block-uniform, before any sync

    const int h    = job % NH;
    const int tile = job / NH;
    const int tz = tile % TZN;
    const int ty = (tile / TZN) % TYN;
    const int tx = tile / (TZN * TYN);
    const int x0 = tx * TX, y0 = ty * TY, z0 = tz * TZ;

    const int tid = threadIdx.x;

    // ---- rpb: block-uniform -> scalar loads into SGPRs ----
    float rk[NTOK];
    {
        const float* rb = rpb + h * NTOK;
        #pragma unroll
        for (int kk = 0; kk < NTOK; ++kk) rk[kk] = rb[kk];
    }

    // ---- Stage k halo as f16: 600 whole-voxel jobs, 3 rounds ----
    #pragma unroll
    for (int it = 0; it < 3; ++it) {
        const int n = tid + it * 256;
        if (n < NHALO) {
            const int hx = n / (HY * HZ);
            const int r  = n - hx * (HY * HZ);
            const int hy = r / HZ;
            const int hz = r - hy * HZ;
            const int gx = x0 - 1 + hx;
            const int gy = y0 - 1 + hy;
            const int gz = z0 - 1 + hz;
            I4H u;
            u.v[0] = make_int4(0, 0, 0, 0);
            u.v[1] = make_int4(0, 0, 0, 0);
            if (((unsigned)gx < DH) & ((unsigned)gy < DW) & ((unsigned)gz < DT)) {
                const float* src = k + ((size_t)((gx * DW + gy) * DT + gz)) * NC
                                     + h * HD;
                const float4 a = *(const float4*)(src);
                const float4 b = *(const float4*)(src + 4);
                const float4 c = *(const float4*)(src + 8);
                const float4 d = *(const float4*)(src + 12);
                u.h[0] = pkrtz(a.x, a.y);
                u.h[1] = pkrtz(a.z, a.w);
                u.h[2] = pkrtz(b.x, b.y);
                u.h[3] = pkrtz(b.z, b.w);
                u.h[4] = pkrtz(c.x, c.y);
                u.h[5] = pkrtz(c.z, c.w);
                u.h[6] = pkrtz(d.x, d.y);
                u.h[7] = pkrtz(d.z, d.w);
            }
            const int p = hy & 1;   // row parity (hx*6 is even)
            s_k[(n * 2 + 0) ^ p] = u.v[0];
            s_k[(n * 2 + 1) ^ p] = u.v[1];
        }
    }

    // ---- q fragment direct, unscaled (scale folded into logit fma) ----
    const int lz = tid & (TZ - 1);
    const int ly = (tid >> 3) & (TY - 1);
    const int lx = tid >> 5;
    const int vox = ((x0 + lx) * DW + (y0 + ly)) * DT + (z0 + lz);

    hh2 qh[8];
    {
        const float4* qv = (const float4*)(q + (size_t)vox * NC + h * HD);
        const float4 a = qv[0], b = qv[1], c = qv[2], d = qv[3];
        qh[0] = pkrtz(a.x, a.y);
        qh[1] = pkrtz(a.z, a.w);
        qh[2] = pkrtz(b.x, b.y);
        qh[3] = pkrtz(b.z, b.w);
        qh[4] = pkrtz(c.x, c.y);
        qh[5] = pkrtz(c.z, c.w);
        qh[6] = pkrtz(d.x, d.y);
        qh[7] = pkrtz(d.z, d.w);
    }

    __syncthreads();

    // ---- 27 neighbor dots (2x swizzled ds_read_b128 + 8x v_dot2 each) ----
    float l[NTOK];
    #pragma unroll
    for (int i = 0; i < 3; ++i) {
        #pragma unroll
        for (int j = 0; j < 3; ++j) {
            const int base = ((lx + i) * HY + (ly + j)) * HZ + lz;
            const int p = (ly + j) & 1;   // row parity of this read row
            #pragma unroll
            for (int ll = 0; ll < 3; ++ll) {
                const int n = base + ll;
                I4H u;
                u.v[0] = s_k[(n * 2 + 0) ^ p];
                u.v[1] = s_k[(n * 2 + 1) ^ p];
                float d = 0.0f;
                d = dot2acc(qh[0], u.h[0], d);
                d = dot2acc(qh[1], u.h[1], d);
                d = dot2acc(qh[2], u.h[2], d);
                d = dot2acc(qh[3], u.h[3], d);
                d = dot2acc(qh[4], u.h[4], d);
                d = dot2acc(qh[5], u.h[5], d);
                d = dot2acc(qh[6], u.h[6], d);
                d = dot2acc(qh[7], u.h[7], d);
                const int kk = (i * 3 + j) * 3 + ll;
                l[kk] = fmaf(d, 0.25f, rk[kk]);   // scale = 16^-0.5
            }
        }
    }

    // ---- max via fmax tree ----
    float g0 = fmaxf(fmaxf(l[0],  l[1]),  l[2]);
    float g1 = fmaxf(fmaxf(l[3],  l[4]),  l[5]);
    float g2 = fmaxf(fmaxf(l[6],  l[7]),  l[8]);
    float g3 = fmaxf(fmaxf(l[9],  l[10]), l[11]);
    float g4 = fmaxf(fmaxf(l[12], l[13]), l[14]);
    float g5 = fmaxf(fmaxf(l[15], l[16]), l[17]);
    float g6 = fmaxf(fmaxf(l[18], l[19]), l[20]);
    float g7 = fmaxf(fmaxf(l[21], l[22]), l[23]);
    float g8 = fmaxf(fmaxf(l[24], l[25]), l[26]);
    float t0 = fmaxf(fmaxf(g0, g1), g2);
    float t1 = fmaxf(fmaxf(g3, g4), g5);
    float t2 = fmaxf(fmaxf(g6, g7), g8);
    const float m = fmaxf(fmaxf(t0, t1), t2);

    // ---- exp in base-2 domain ----
    const float LOG2E = 1.44269504f;
    const float nm2 = -m * LOG2E;
    float e[NTOK];
    #pragma unroll
    for (int kk = 0; kk < NTOK; ++kk)
        e[kk] = exp2f(fmaf(l[kk], LOG2E, nm2));

    // ---- displacement via 9 plane-partials ----
    float s[9], zp[9];
    #pragma unroll
    for (int g = 0; g < 9; ++g) {
        s[g]  = (e[g * 3] + e[g * 3 + 1]) + e[g * 3 + 2];
        zp[g] = e[g * 3 + 2] - e[g * 3];
    }
    const float sum = ((s[0] + s[1]) + (s[2] + s[3]))
                    + ((s[4] + s[5]) + (s[6] + s[7])) + s[8];
    const float szs = ((zp[0] + zp[1]) + (zp[2] + zp[3]))
                    + ((zp[4] + zp[5]) + (zp[6] + zp[7])) + zp[8];
    const float sxs = ((s[6] + s[7]) + s[8]) - ((s[0] + s[1]) + s[2]);
    const float sys = ((s[2] + s[5]) + s[8]) - ((s[0] + s[3]) + s[6]);

    const float inv = __builtin_amdgcn_rcpf(sum);

    out[((size_t)(h * 3 + 0)) * NVOX + vox] = sxs * inv;
    out[((size_t)(h * 3 + 1)) * NVOX + vox] = sys * inv;
    out[((size_t)(h * 3 + 2)) * NVOX + vox] = szs * inv;
}

extern "C" void kernel_launch(void* const* d_in, const int* in_sizes, int n_in,
                              void* d_out, int out_size, void* d_ws, size_t ws_size,
                              hipStream_t stream) {
    const float* q   = (const float*)d_in[0];
    const float* k   = (const float*)d_in[1];
    const float* rpb = (const float*)d_in[2];
    float* out = (float*)d_out;

    natt_disp_kernel<<<GRID, 256, 0, stream>>>(q, k, rpb, out);
}